// Round 7
// baseline (213.920 us; speedup 1.0000x reference)
//
#include <hip/hip_runtime.h>
#include <stdint.h>

#define MAX_ITERS 20
#define EPSV 1e-7f
#define CLIPV 1e-7f
#define PI_F 3.14159265358979f
#define PIO2_F 1.57079632679490f

typedef __attribute__((ext_vector_type(8))) short short8;
typedef __attribute__((ext_vector_type(4))) float f4;

__device__ __forceinline__ f4 mfma_bf16(short8 a, short8 b, f4 c) {
    return __builtin_amdgcn_mfma_f32_16x16x32_bf16(a, b, c, 0, 0, 0);
}

__device__ __forceinline__ float rl(float v, int l) {
    return __int_as_float(__builtin_amdgcn_readlane(__float_as_int(v), l));
}

// DPP ctrls used (TRUE lane semantics):
//   0xB1  quad_perm(1,0,3,2)  = lane ^ 1
//   0x4E  quad_perm(2,3,0,1)  = lane ^ 2
//   0x128 row_ror:8 (16-lane) = lane ^ 8
//   0x141 row_half_mirror     = lane ^ 7   (xor4-equivalent ONLY on quad-uniform data)
//   0x140 row_mirror          = lane ^ 15  (xor8-equivalent ONLY on 8-uniform data)
template <int CTRL>
__device__ __forceinline__ float dpp_add(float v) {
    int p = __builtin_amdgcn_update_dpp(0, __float_as_int(v), CTRL, 0xF, 0xF, true);
    return v + __int_as_float(p);
}
template <int CTRL>
__device__ __forceinline__ float dpp_mov(float v) {
    return __int_as_float(__builtin_amdgcn_update_dpp(0, __float_as_int(v), CTRL, 0xF, 0xF, true));
}

// ds_swizzle with compile-time pattern (builtin requires a constant integer)
template <int PAT>
__device__ __forceinline__ float swz(float v) {
    return __int_as_float(__builtin_amdgcn_ds_swizzle(__float_as_int(v), PAT));
}

// sum within each 16-lane row. Mirror ctrls are valid here because data is
// quad-uniform (resp. 8-uniform) by the time they are applied.
__device__ __forceinline__ float rowsum16(float v) {
    v = dpp_add<0xB1>(v);
    v = dpp_add<0x4E>(v);
    v = dpp_add<0x141>(v);
    v = dpp_add<0x140>(v);
    return v;
}

// per-32-half sum via readlane (pure VALU; result per-half uniform)
__device__ __forceinline__ float halfsum_rl(float v, bool hB) {
    v = rowsum16(v);
    float sA = rl(v, 0) + rl(v, 16);
    float sB = rl(v, 32) + rl(v, 48);
    return hB ? sB : sA;
}

// per-32-half sum via one ds_swizzle xor16 (use where latency is hidden)
__device__ __forceinline__ float halfsum_sw(float v) {
    v = rowsum16(v);
    return v + swz<0x401F>(v);   // xor16 within each 32-lane half
}

__device__ __forceinline__ float fast_acos(float x) {
    float a = fabsf(x);
    bool big = a > 0.5f;
    float z = big ? 0.5f * (1.0f - a) : x * x;
    float s = big ? sqrtf(z) : x;
    float p = fmaf(z, fmaf(z, fmaf(z, fmaf(z, 4.2163199048e-2f, 2.4181311049e-2f),
                                   4.5470025998e-2f), 7.4953002686e-2f),
                   1.6666752422e-1f);
    float r = fmaf(s * z, p, s);
    float big_val = (x < 0.0f) ? (PI_F - 2.0f * r) : (2.0f * r);
    return big ? big_val : (PIO2_F - r);
}

__device__ __forceinline__ void cvt_hilo(const float* v, short8& hi, short8& lo) {
#pragma unroll
    for (int i = 0; i < 8; ++i) {
        float x = v[i];
        uint32_t u = __float_as_uint(x);
        float hf = __uint_as_float(u & 0xFFFF0000u);
        float lf = x - hf;
        hi[i] = (short)(u >> 16);
        lo[i] = (short)(__float_as_uint(lf) >> 16);
    }
}

// Correct Gray-code sub-walk over bits {0,1,3}: masks b, b^1, b^3, b^2,
// b^10, b^11, b^9, b^8  — covers {b ^ {0,1,2,3,8,9,10,11}}. All flips are
// literal lane-xors (0xB1, 0x4E, 0x128).
#define CHAIN8(cur, acc, B)                                          \
    acc = Grow2[B] * cur;                                            \
    cur = dpp_mov<0xB1>(cur);  acc = fmaf(Grow2[(B)^1],  cur, acc);  \
    cur = dpp_mov<0x4E>(cur);  acc = fmaf(Grow2[(B)^3],  cur, acc);  \
    cur = dpp_mov<0xB1>(cur);  acc = fmaf(Grow2[(B)^2],  cur, acc);  \
    cur = dpp_mov<0x128>(cur); acc = fmaf(Grow2[(B)^10], cur, acc);  \
    cur = dpp_mov<0xB1>(cur);  acc = fmaf(Grow2[(B)^11], cur, acc);  \
    cur = dpp_mov<0x4E>(cur);  acc = fmaf(Grow2[(B)^9],  cur, acc);  \
    cur = dpp_mov<0xB1>(cur);  acc = fmaf(Grow2[(B)^8],  cur, acc);

// async global->LDS, 16B per lane; LDS dest = ldsp + lane*16 (HW rule)
#define GLOAD_LDS16(srcp, ldsp)                                                   \
    __builtin_amdgcn_global_load_lds(                                             \
        (const __attribute__((address_space(1))) uint32_t*)(srcp),                \
        (__attribute__((address_space(3))) uint32_t*)(ldsp), 16, 0, 0)

#define WAIT_VM(N) do {                                        \
        asm volatile("s_waitcnt vmcnt(" #N ")" ::: "memory");  \
        __builtin_amdgcn_sched_barrier(0);                     \
    } while (0)

// swizzled G element address (floats), 32x32 tile, granule-XOR on (row&7)
__device__ __forceinline__ int gidx(int row, int j) {
    return row * 32 + ((((j >> 2) ^ (row & 7)) << 2) | (j & 3));
}

// ============================================================================
// 4 groups/block (128 threads = 2 waves, 2 groups/wave: lanes 0-31 own g0,
// lanes 32-63 own g0+1). Per wave: three 4-KB LDS slots; K-quarter staging
// runs a counted-vmcnt pipeline (2 tiles always in flight, vmcnt(4) waits).
// G0 parks in slot2, G1 in slot0 after their tiles die. Karcher loop uses a
// corrected literal-xor Gray matvec: 4 independent 7-step DPP chains seeded
// by parallel ds_swizzles (xor4/xor16/xor20).
// ============================================================================
__global__ void __launch_bounds__(128, 4) karcher(const float* __restrict__ X,
                                                  float* __restrict__ ws,
                                                  int n_groups) {
    __shared__ float lds[2][3072];   // per-wave: slot0|slot1|slot2 (4 KB each)
    __shared__ float sInv[2][64];
    __shared__ float sPart[4];

    const int lane = threadIdx.x & 63;
    const int wid  = threadIdx.x >> 6;           // 0..1
    const int g0   = blockIdx.x * 4 + wid * 2;   // first of this wave's 2 groups
    if (g0 >= n_groups) return;   // 8000 % 4 == 0: never diverges

    const int col  = lane & 15;
    const int quad = lane >> 4;

    float* slot0 = lds[wid];
    float* slot1 = lds[wid] + 1024;
    float* slot2 = lds[wid] + 2048;

    // stage one 32x32-float K-quarter, coalesced, source pre-swizzled.
    // LDS granule (rr,g2) receives X granule (rr, g2 ^ (rr&7))  [involution]
    const int rrl = lane >> 3;   // 0..7
    const int g2l = lane & 7;
    auto stage = [&](const float* Xg, int kq, float* slot) {
#pragma unroll
        for (int i = 0; i < 4; ++i) {
            int rr  = i * 8 + rrl;
            int g2s = g2l ^ (rr & 7);
            GLOAD_LDS16(Xg + rr * 128 + kq * 32 + g2s * 4, slot + i * 256);
        }
    };

    const int x0 = col & 7;
    const int b0 = col * 32;
    const int b1 = (col + 16) * 32;
    f4 a00 = {0.f, 0.f, 0.f, 0.f}, a01 = a00, a10 = a00, a11 = a00;
    auto gramq = [&](const float* st) {
        int s0 = ((quad * 2 + 0) ^ x0) * 4;
        int s1 = ((quad * 2 + 1) ^ x0) * 4;
        float r0[8], r1[8];
        *(float4*)(r0)     = *(const float4*)(st + b0 + s0);
        *(float4*)(r0 + 4) = *(const float4*)(st + b0 + s1);
        *(float4*)(r1)     = *(const float4*)(st + b1 + s0);
        *(float4*)(r1 + 4) = *(const float4*)(st + b1 + s1);
        short8 H0, L0, H1, L1;
        cvt_hilo(r0, H0, L0);
        cvt_hilo(r1, H1, L1);
        a00 = mfma_bf16(H0, H0, a00);
        a00 = mfma_bf16(H0, L0, a00);
        a00 = mfma_bf16(L0, H0, a00);
        a01 = mfma_bf16(H0, H1, a01);
        a01 = mfma_bf16(H0, L1, a01);
        a01 = mfma_bf16(L0, H1, a01);
        a10 = mfma_bf16(H1, H0, a10);
        a10 = mfma_bf16(H1, L0, a10);
        a10 = mfma_bf16(L1, H0, a10);
        a11 = mfma_bf16(H1, H1, a11);
        a11 = mfma_bf16(H1, L1, a11);
        a11 = mfma_bf16(L1, H1, a11);
    };
    auto writeG = [&](float* Gs) {
#pragma unroll
        for (int i = 0; i < 4; ++i) {   // C/D: col=lane&15, row=quad*4+i (G sym)
            int rw = quad * 4 + i;
            Gs[gidx(rw,      col)]      = a00[i];
            Gs[gidx(rw,      col + 16)] = a01[i];
            Gs[gidx(rw + 16, col)]      = a10[i];
            Gs[gidx(rw + 16, col + 16)] = a11[i];
        }
    };

    // ---- pipelined staging + Gram: always 2 quarter-tiles in flight ---------
    // (gram's ds_read results are consumed -- lgkmcnt waits precede the next
    //  stage() in program order -- so DMA reuse of a slot is hazard-free.)
    {
        const float* Xa = X + (size_t)g0 * 4096;
        const float* Xb = X + (size_t)(g0 + 1) * 4096;
        stage(Xa, 0, slot0);
        stage(Xa, 1, slot1);                        // vm=8
        WAIT_VM(4);  gramq(slot0);  stage(Xa, 2, slot0);   // vm=8
        WAIT_VM(4);  gramq(slot1);  stage(Xa, 3, slot1);   // vm=8
        WAIT_VM(4);  gramq(slot0);  stage(Xb, 0, slot0);   // vm=8
        WAIT_VM(4);  gramq(slot1);                  // group0 Gram done; vm=4
        writeG(slot2);                              // G0 -> slot2
        a00 = {0.f, 0.f, 0.f, 0.f}; a01 = a00; a10 = a00; a11 = a00;
        stage(Xb, 1, slot1);                        // vm=8
        WAIT_VM(4);  gramq(slot0);  stage(Xb, 2, slot0);   // vm=8
        WAIT_VM(4);  gramq(slot1);  stage(Xb, 3, slot1);   // vm=8
        WAIT_VM(4);  gramq(slot0);
        WAIT_VM(0);  gramq(slot1);
        writeG(slot0);                              // G1 -> slot0
    }

    // ---- Phase 3: xor-permuted normalized Gram row into VGPRs ---------------
    const int  half = lane >> 5;
    const bool hB   = half != 0;
    const int  r    = lane & 31;
    const float* Gh = hB ? slot0 : slot2;

    float inv = 1.0f / fmaxf(sqrtf(Gh[gidx(r, r)]), 1e-12f);
    sInv[wid][lane] = inv;                 // [half*32 + r]
    const float* sI = sInv[wid] + half * 32;

    float Grow2[32];
#pragma unroll
    for (int gg = 0; gg < 32; ++gg) {
        int j = r ^ gg;
        Grow2[gg] = Gh[gidx(r, j)] * (inv * sI[j]);
    }

    // ---- Phase 4: mu0 = normalize(mean(Xn)) in coefficient space ------------
    float a = 1.0f / 32.0f;
    float ga;
    {
        float s0 = 0, s1 = 0, s2 = 0, s3 = 0;
#pragma unroll
        for (int gg = 0; gg < 8; ++gg) {
            s0 += Grow2[gg];
            s1 += Grow2[gg + 8];
            s2 += Grow2[gg + 16];
            s3 += Grow2[gg + 24];
        }
        ga = ((s0 + s1) + (s2 + s3)) * (1.0f / 32.0f);
        float n2   = halfsum_rl(a * ga, hB);
        float inv0 = 1.0f / fmaxf(sqrtf(n2), 1e-12f);
        a  *= inv0;
        ga *= inv0;
    }

    // ---- Phase 5: Karcher iterations, corrected 4-chain Gray matvec ---------
    for (int it = 0; it < MAX_ITERS; ++it) {
        float x  = fminf(fmaxf(ga, -1.0f + CLIPV), 1.0f - CLIPV);
        float th = fast_acos(x);
        float st = fmaxf(sqrtf(fmaxf(1.0f - x * x, 0.0f)), EPSV);
        float w  = __fdividef(th, st);

        // 3 seed swizzles issue in parallel (xor4, xor16, xor20 within halves)
        float w4  = swz<0x101F>(w);
        float w16 = swz<0x401F>(w);
        float w20 = swz<0x501F>(w);
        float C = halfsum_sw(w * ga);   // sum_n w_n dot_n (latency hidden)

        float c0 = w,  c1 = w4, c2 = w16, c3 = w20;
        float A0, A1, A2, A3;
        CHAIN8(c0, A0, 0)
        CHAIN8(c1, A1, 4)
        CHAIN8(c2, A2, 16)
        CHAIN8(c3, A3, 20)
        float gw = (A0 + A1) + (A2 + A3);          // (G w)_r, exact

        float gb   = (gw - C * ga) * (1.0f / 32.0f);
        float beta = (w  - C * a ) * (1.0f / 32.0f);

        float vv = halfsum_rl(beta * gb, hB);      // ||v||^2 = beta^T G beta
        float vs = fmaxf(sqrtf(fmaxf(vv, 0.0f)), EPSV);
        float cv = __cosf(vs);
        float sv = __fdividef(__sinf(vs), vs);
        a  = fmaf(sv, beta, cv * a);               // exp map (v perp mu)
        ga = fmaf(sv, gb, cv * ga);
        if (__all(vs < 1e-6f)) break;  // both halves converged
    }

    // ---- Phase 6: per-block partial loss ------------------------------------
    float xf = fminf(fmaxf(ga, -1.0f + CLIPV), 1.0f - CLIPV);
    float t  = fast_acos(xf);
    float ls = halfsum_rl(t * t, hB);   // per-half uniform
    if (r == 0) sPart[wid * 2 + half] = ls;
    __syncthreads();
    if (threadIdx.x == 0)
        ws[blockIdx.x] = (sPart[0] + sPart[1]) + (sPart[2] + sPart[3]);
}

__global__ void __launch_bounds__(256) reduce_partials(const float* __restrict__ ws,
                                                       float* __restrict__ out,
                                                       int n, float scale) {
    __shared__ float sred[4];
    float s = 0.f;
    for (int i = threadIdx.x; i < n; i += 256) s += ws[i];
#pragma unroll
    for (int m = 32; m >= 1; m >>= 1) s += __shfl_xor(s, m, 64);
    const int lane = threadIdx.x & 63, wid = threadIdx.x >> 6;
    if (lane == 0) sred[wid] = s;
    __syncthreads();
    if (threadIdx.x == 0)
        out[0] = ((sred[0] + sred[1]) + (sred[2] + sred[3])) * scale;
}

extern "C" void kernel_launch(void* const* d_in, const int* in_sizes, int n_in,
                              void* d_out, int out_size, void* d_ws, size_t ws_size,
                              hipStream_t stream) {
    const float* X = (const float*)d_in[0];
    float* out = (float*)d_out;
    float* ws = (float*)d_ws;
    int n_groups = in_sizes[0] / (32 * 128);   // 8000
    int blocks = (n_groups + 3) / 4;           // 2000 blocks, 2 groups/wave
    karcher<<<blocks, 128, 0, stream>>>(X, ws, n_groups);
    reduce_partials<<<1, 256, 0, stream>>>(ws, out, blocks, 1.0f / (float)n_groups);
}